// Round 1
// baseline (4100.150 us; speedup 1.0000x reference)
//
#include <hip/hip_runtime.h>
#include <hip/hip_bf16.h>

#define BB 256      // batch
#define CC 2048     // code_num
#define HD 1024     // hidden
#define TT 64       // max_len
#define H3 3072

typedef __attribute__((ext_vector_type(8))) short bf16x8;
typedef __attribute__((ext_vector_type(4))) float f32x4;

__device__ __forceinline__ float sigmoidf_(float x){ return 1.0f/(1.0f+__expf(-x)); }
__device__ __forceinline__ float tanhf_(float x){ float e=__expf(2.0f*x); return 1.0f - 2.0f/(e+1.0f); }

__device__ __forceinline__ bf16x8 ldfrag(const __hip_bfloat16* p){
  return *reinterpret_cast<const bf16x8*>(p);
}
__device__ __forceinline__ unsigned short bfbits(float x){
  __hip_bfloat16 b = __float2bfloat16(x);
  return *reinterpret_cast<unsigned short*>(&b);
}

__global__ void cvt_f32_bf16(const float* __restrict__ in, __hip_bfloat16* __restrict__ out, int n){
  int i = (blockIdx.x*blockDim.x + threadIdx.x)*4;
  int stride = gridDim.x*blockDim.x*4;
  for (; i < n; i += stride){
    float4 v = *reinterpret_cast<const float4*>(in + i);
    ushort4 s;
    s.x = bfbits(v.x); s.y = bfbits(v.y); s.z = bfbits(v.z); s.w = bfbits(v.w);
    *reinterpret_cast<ushort4*>(out + i) = s;
  }
}

// Computes h_new for step t. Wave tile: 16(m) x 16(j) of h_new, 6 accumulators
// (i_r,i_z,i_n over K=C; h_r,h_z,h_n over K=H). Block: 4 waves stacked on M
// (tile 64x16). Grid: (256/64) * (1024/16) = 256 blocks.
__global__ __launch_bounds__(256) void cell_kernel(
    const __hip_bfloat16* __restrict__ codes,   // [B][C] bf16
    const __hip_bfloat16* __restrict__ hprev,   // [B][H] bf16 (unused if first)
    const __hip_bfloat16* __restrict__ Wih,     // [3H][C] bf16
    const __hip_bfloat16* __restrict__ Whh,     // [3H][H] bf16
    const float* __restrict__ bih,
    const float* __restrict__ bhh,
    float* __restrict__ hiddens,                // [B][T][H] fp32 out
    __hip_bfloat16* __restrict__ hnext,         // [B][H] bf16 out
    int t, int first)
{
  const int tid  = threadIdx.x;
  const int lane = tid & 63;
  const int wid  = tid >> 6;
  const int bm   = blockIdx.x & 3;
  const int bj   = blockIdx.x >> 2;
  const int m0   = bm*64 + wid*16;
  const int j0   = bj*16;
  const int rl   = lane & 15;
  const int kg   = lane >> 4;

  const __hip_bfloat16* arow = codes + (size_t)(m0+rl)*CC + kg*8;
  const __hip_bfloat16* wr   = Wih   + (size_t)(j0+rl)*CC + kg*8;
  const __hip_bfloat16* wz   = wr + (size_t)HD*CC;
  const __hip_bfloat16* wn   = wz + (size_t)HD*CC;

  f32x4 zz4 = {0.f,0.f,0.f,0.f};
  f32x4 a0=zz4, a1=zz4, a2=zz4, a3=zz4, a4=zz4, a5=zz4;

#pragma unroll 4
  for (int k = 0; k < CC; k += 32){
    bf16x8 a  = ldfrag(arow + k);
    bf16x8 fr = ldfrag(wr + k);
    bf16x8 fz = ldfrag(wz + k);
    bf16x8 fn = ldfrag(wn + k);
    a0 = __builtin_amdgcn_mfma_f32_16x16x32_bf16(a, fr, a0, 0, 0, 0);
    a1 = __builtin_amdgcn_mfma_f32_16x16x32_bf16(a, fz, a1, 0, 0, 0);
    a2 = __builtin_amdgcn_mfma_f32_16x16x32_bf16(a, fn, a2, 0, 0, 0);
  }

  if (!first){
    const __hip_bfloat16* hrow = hprev + (size_t)(m0+rl)*HD + kg*8;
    const __hip_bfloat16* vr   = Whh   + (size_t)(j0+rl)*HD + kg*8;
    const __hip_bfloat16* vz   = vr + (size_t)HD*HD;
    const __hip_bfloat16* vn   = vz + (size_t)HD*HD;
#pragma unroll 4
    for (int k = 0; k < HD; k += 32){
      bf16x8 a  = ldfrag(hrow + k);
      bf16x8 fr = ldfrag(vr + k);
      bf16x8 fz = ldfrag(vz + k);
      bf16x8 fn = ldfrag(vn + k);
      a3 = __builtin_amdgcn_mfma_f32_16x16x32_bf16(a, fr, a3, 0, 0, 0);
      a4 = __builtin_amdgcn_mfma_f32_16x16x32_bf16(a, fz, a4, 0, 0, 0);
      a5 = __builtin_amdgcn_mfma_f32_16x16x32_bf16(a, fn, a5, 0, 0, 0);
    }
  }

  // Epilogue: D layout col = lane&15, row = (lane>>4)*4 + q
  const int j = j0 + rl;
  const float bir = bih[j], biz = bih[j+HD], bin = bih[j+2*HD];
  const float bhr = bhh[j], bhz = bhh[j+HD], bhn = bhh[j+2*HD];
  const int rbase = m0 + kg*4;
#pragma unroll
  for (int q = 0; q < 4; q++){
    const int brow = rbase + q;
    float ir = a0[q] + bir, iz = a1[q] + biz, inn = a2[q] + bin;
    float hr = a3[q] + bhr, hz = a4[q] + bhz, hn = a5[q] + bhn;
    float r = sigmoidf_(ir + hr);
    float z = sigmoidf_(iz + hz);
    float n = tanhf_(inn + r*hn);
    float hp = first ? 0.0f : __bfloat162float(hprev[(size_t)brow*HD + j]);
    float hv = (1.0f - z)*n + z*hp;
    hiddens[(size_t)brow*TT*HD + (size_t)t*HD + j] = hv;
    hnext[(size_t)brow*HD + j] = __float2bfloat16(hv);
  }
}

// codes_{t} = sigmoid(act @ W_out^T + b_out). Wave tile 16(m) x 32(c).
// Block 4 waves stacked on M (tile 64x32). Grid 4 * 64 = 256 blocks.
__global__ __launch_bounds__(256) void logits_kernel(
    const __hip_bfloat16* __restrict__ act,     // [B][H] bf16
    const __hip_bfloat16* __restrict__ Wout,    // [C][H] bf16
    const float* __restrict__ bout,
    float* __restrict__ samples,                // [B][T][C] fp32 out
    __hip_bfloat16* __restrict__ codes_out,     // [B][C] bf16 out
    int t)
{
  const int tid  = threadIdx.x;
  const int lane = tid & 63;
  const int wid  = tid >> 6;
  const int bm   = blockIdx.x & 3;
  const int bc   = blockIdx.x >> 2;
  const int m0   = bm*64 + wid*16;
  const int c0   = bc*32;
  const int rl   = lane & 15;
  const int kg   = lane >> 4;

  const __hip_bfloat16* arow = act  + (size_t)(m0+rl)*HD + kg*8;
  const __hip_bfloat16* w0   = Wout + (size_t)(c0+rl)*HD + kg*8;
  const __hip_bfloat16* w1   = w0 + (size_t)16*HD;

  f32x4 zz4 = {0.f,0.f,0.f,0.f};
  f32x4 acc0 = zz4, acc1 = zz4;

#pragma unroll 4
  for (int k = 0; k < HD; k += 32){
    bf16x8 a  = ldfrag(arow + k);
    bf16x8 f0 = ldfrag(w0 + k);
    bf16x8 f1 = ldfrag(w1 + k);
    acc0 = __builtin_amdgcn_mfma_f32_16x16x32_bf16(a, f0, acc0, 0, 0, 0);
    acc1 = __builtin_amdgcn_mfma_f32_16x16x32_bf16(a, f1, acc1, 0, 0, 0);
  }

  const int ca = c0 + rl, cb = ca + 16;
  const float b0 = bout[ca], b1 = bout[cb];
  const int rbase = m0 + kg*4;
#pragma unroll
  for (int q = 0; q < 4; q++){
    const int brow = rbase + q;
    float s0 = sigmoidf_(acc0[q] + b0);
    float s1 = sigmoidf_(acc1[q] + b1);
    samples[(size_t)brow*TT*CC + (size_t)t*CC + ca] = s0;
    samples[(size_t)brow*TT*CC + (size_t)t*CC + cb] = s1;
    codes_out[(size_t)brow*CC + ca] = __float2bfloat16(s0);
    codes_out[(size_t)brow*CC + cb] = __float2bfloat16(s1);
  }
}

extern "C" void kernel_launch(void* const* d_in, const int* in_sizes, int n_in,
                              void* d_out, int out_size, void* d_ws, size_t ws_size,
                              hipStream_t stream) {
  const float* noise = (const float*)d_in[0];
  const float* W_ih  = (const float*)d_in[1];
  const float* b_ih  = (const float*)d_in[2];
  const float* W_hh  = (const float*)d_in[3];
  const float* b_hh  = (const float*)d_in[4];
  const float* W_out = (const float*)d_in[5];
  const float* b_out = (const float*)d_in[6];

  float* samples = (float*)d_out;                       // [B][T][C]
  float* hiddens = samples + (size_t)BB*TT*CC;          // [B][T][H]

  char* w = (char*)d_ws;
  __hip_bfloat16* wih16 = (__hip_bfloat16*)w;  w += (size_t)H3*CC*2;
  __hip_bfloat16* whh16 = (__hip_bfloat16*)w;  w += (size_t)H3*HD*2;
  __hip_bfloat16* wout16= (__hip_bfloat16*)w;  w += (size_t)CC*HD*2;
  __hip_bfloat16* noise16=(__hip_bfloat16*)w;  w += (size_t)BB*HD*2;
  __hip_bfloat16* codes16=(__hip_bfloat16*)w;  w += (size_t)BB*CC*2;
  __hip_bfloat16* h16a  = (__hip_bfloat16*)w;  w += (size_t)BB*HD*2;
  __hip_bfloat16* h16b  = (__hip_bfloat16*)w;  w += (size_t)BB*HD*2;

  cvt_f32_bf16<<<2048, 256, 0, stream>>>(W_ih,  wih16,  H3*CC);
  cvt_f32_bf16<<<2048, 256, 0, stream>>>(W_hh,  whh16,  H3*HD);
  cvt_f32_bf16<<<1024, 256, 0, stream>>>(W_out, wout16, CC*HD);
  cvt_f32_bf16<<<256,  256, 0, stream>>>(noise, noise16, BB*HD);

  // samples[:,0,:] = codes0 = sigmoid(noise @ W_out^T + b_out)
  logits_kernel<<<256, 256, 0, stream>>>(noise16, wout16, b_out, samples, codes16, 0);

  for (int t = 0; t < TT; t++){
    __hip_bfloat16* hprev = (t & 1) ? h16a : h16b;   // h16[(t-1)&1]
    __hip_bfloat16* hnext = (t & 1) ? h16b : h16a;   // h16[t&1]
    cell_kernel<<<256, 256, 0, stream>>>(codes16, hprev, wih16, whh16,
                                         b_ih, b_hh, hiddens, hnext,
                                         t, (t == 0) ? 1 : 0);
    if (t < TT-1){
      logits_kernel<<<256, 256, 0, stream>>>(hnext, wout16, b_out,
                                             samples, codes16, t+1);
    }
  }
}

// Round 2
// 3796.164 us; speedup vs baseline: 1.0801x; 1.0801x over previous
//
#include <hip/hip_runtime.h>
#include <hip/hip_bf16.h>

#define BB 256      // batch
#define CC 2048     // code_num
#define HD 1024     // hidden
#define TT 64       // max_len
#define H3 3072

typedef __attribute__((ext_vector_type(8))) short bf16x8;
typedef __attribute__((ext_vector_type(4))) float f32x4;

__device__ __forceinline__ float sigmoidf_(float x){ return 1.0f/(1.0f+__expf(-x)); }
__device__ __forceinline__ float tanhf_(float x){ float e=__expf(2.0f*x); return 1.0f - 2.0f/(e+1.0f); }

__device__ __forceinline__ bf16x8 ldfrag(const __hip_bfloat16* p){
  return *reinterpret_cast<const bf16x8*>(p);
}
__device__ __forceinline__ unsigned short bfbits(float x){
  __hip_bfloat16 b = __float2bfloat16(x);
  return *reinterpret_cast<unsigned short*>(&b);
}

__global__ void cvt_f32_bf16(const float* __restrict__ in, __hip_bfloat16* __restrict__ out, int n){
  int i = (blockIdx.x*blockDim.x + threadIdx.x)*4;
  int stride = gridDim.x*blockDim.x*4;
  for (; i < n; i += stride){
    float4 v = *reinterpret_cast<const float4*>(in + i);
    ushort4 s;
    s.x = bfbits(v.x); s.y = bfbits(v.y); s.z = bfbits(v.z); s.w = bfbits(v.w);
    *reinterpret_cast<ushort4*>(out + i) = s;
  }
}

// h_new for step t. Block: 1024 threads = 16 waves. Block tile: 64(m) x 16(j),
// all 3 gates. Wave (ws = wid&3 -> m-sub of 16 rows, kc = wid>>2 -> K-chunk).
// Each wave computes partial sums over its K chunk (512 of C, 256 of H);
// two-stage LDS reduction combines the 4 K-chunks; kc==0 waves do gate math.
// Grid: (256/64) * (1024/16) = 256 blocks.
__global__ __launch_bounds__(1024, 4) void cell_kernel(
    const __hip_bfloat16* __restrict__ codes,   // [B][C] bf16
    const __hip_bfloat16* __restrict__ hprev,   // [B][H] bf16 (unused if first)
    const __hip_bfloat16* __restrict__ Wih,     // [3H][C] bf16
    const __hip_bfloat16* __restrict__ Whh,     // [3H][H] bf16
    const float* __restrict__ bih,
    const float* __restrict__ bhh,
    float* __restrict__ hiddens,                // [B][T][H] fp32 out
    __hip_bfloat16* __restrict__ hnext,         // [B][H] bf16 out
    int t, int first)
{
  __shared__ float red[8*64*25];   // 8 slots x 64 lanes x (24 floats + pad)

  const int tid  = threadIdx.x;
  const int lane = tid & 63;
  const int wid  = tid >> 6;     // 0..15
  const int ws   = wid & 3;      // m-sub select
  const int kc   = wid >> 2;     // K-chunk select (0..3)
  const int bm   = blockIdx.x & 3;
  const int bj   = blockIdx.x >> 2;
  const int m0   = bm*64 + ws*16;
  const int j0   = bj*16;
  const int rl   = lane & 15;
  const int kg   = lane >> 4;

  const __hip_bfloat16* arow = codes + (size_t)(m0+rl)*CC + kc*512 + kg*8;
  const __hip_bfloat16* wr   = Wih   + (size_t)(j0+rl)*CC + kc*512 + kg*8;
  const __hip_bfloat16* wz   = wr + (size_t)HD*CC;
  const __hip_bfloat16* wn   = wz + (size_t)HD*CC;

  f32x4 zz4 = {0.f,0.f,0.f,0.f};
  f32x4 a0=zz4, a1=zz4, a2=zz4, a3=zz4, a4=zz4, a5=zz4;

#pragma unroll 4
  for (int k = 0; k < 512; k += 32){
    bf16x8 a  = ldfrag(arow + k);
    bf16x8 fr = ldfrag(wr + k);
    bf16x8 fz = ldfrag(wz + k);
    bf16x8 fn = ldfrag(wn + k);
    a0 = __builtin_amdgcn_mfma_f32_16x16x32_bf16(a, fr, a0, 0, 0, 0);
    a1 = __builtin_amdgcn_mfma_f32_16x16x32_bf16(a, fz, a1, 0, 0, 0);
    a2 = __builtin_amdgcn_mfma_f32_16x16x32_bf16(a, fn, a2, 0, 0, 0);
  }

  if (!first){
    const __hip_bfloat16* hrow = hprev + (size_t)(m0+rl)*HD + kc*256 + kg*8;
    const __hip_bfloat16* vr   = Whh   + (size_t)(j0+rl)*HD + kc*256 + kg*8;
    const __hip_bfloat16* vz   = vr + (size_t)HD*HD;
    const __hip_bfloat16* vn   = vz + (size_t)HD*HD;
#pragma unroll 4
    for (int k = 0; k < 256; k += 32){
      bf16x8 a  = ldfrag(hrow + k);
      bf16x8 fr = ldfrag(vr + k);
      bf16x8 fz = ldfrag(vz + k);
      bf16x8 fn = ldfrag(vn + k);
      a3 = __builtin_amdgcn_mfma_f32_16x16x32_bf16(a, fr, a3, 0, 0, 0);
      a4 = __builtin_amdgcn_mfma_f32_16x16x32_bf16(a, fz, a4, 0, 0, 0);
      a5 = __builtin_amdgcn_mfma_f32_16x16x32_bf16(a, fn, a5, 0, 0, 0);
    }
  }

  // ---- two-stage K-chunk reduction through LDS ----
  // stage 1: kc in {2,3} publish; kc in {0,1} absorb.
  if (kc >= 2){
    float* p = &red[((kc-2)*4 + ws)*64*25 + lane*25];
#pragma unroll
    for (int q = 0; q < 4; q++){
      p[q] = a0[q]; p[4+q] = a1[q]; p[8+q] = a2[q];
      p[12+q] = a3[q]; p[16+q] = a4[q]; p[20+q] = a5[q];
    }
  }
  __syncthreads();
  if (kc < 2){
    const float* p = &red[(kc*4 + ws)*64*25 + lane*25];
#pragma unroll
    for (int q = 0; q < 4; q++){
      a0[q] += p[q]; a1[q] += p[4+q]; a2[q] += p[8+q];
      a3[q] += p[12+q]; a4[q] += p[16+q]; a5[q] += p[20+q];
    }
  }
  __syncthreads();
  // stage 2: kc==1 publish; kc==0 absorb.
  if (kc == 1){
    float* p = &red[ws*64*25 + lane*25];
#pragma unroll
    for (int q = 0; q < 4; q++){
      p[q] = a0[q]; p[4+q] = a1[q]; p[8+q] = a2[q];
      p[12+q] = a3[q]; p[16+q] = a4[q]; p[20+q] = a5[q];
    }
  }
  __syncthreads();
  if (kc == 0){
    const float* p = &red[ws*64*25 + lane*25];
#pragma unroll
    for (int q = 0; q < 4; q++){
      a0[q] += p[q]; a1[q] += p[4+q]; a2[q] += p[8+q];
      a3[q] += p[12+q]; a4[q] += p[16+q]; a5[q] += p[20+q];
    }

    // Epilogue: D layout col = lane&15, row = (lane>>4)*4 + q
    const int j = j0 + rl;
    const float bir = bih[j], biz = bih[j+HD], bin = bih[j+2*HD];
    const float bhr = bhh[j], bhz = bhh[j+HD], bhn = bhh[j+2*HD];
    const int rbase = m0 + kg*4;
#pragma unroll
    for (int q = 0; q < 4; q++){
      const int brow = rbase + q;
      float ir = a0[q] + bir, iz = a1[q] + biz, inn = a2[q] + bin;
      float hr = a3[q] + bhr, hz = a4[q] + bhz, hn = a5[q] + bhn;
      float r = sigmoidf_(ir + hr);
      float z = sigmoidf_(iz + hz);
      float n = tanhf_(inn + r*hn);
      float hp = first ? 0.0f : __bfloat162float(hprev[(size_t)brow*HD + j]);
      float hv = (1.0f - z)*n + z*hp;
      hiddens[(size_t)brow*TT*HD + (size_t)t*HD + j] = hv;
      hnext[(size_t)brow*HD + j] = __float2bfloat16(hv);
    }
  }
}

// codes_t = sigmoid(act @ W_out^T + b_out). Block: 1024 threads = 16 waves.
// Block tile 64(m) x 32(c); wave (ws m-sub, kc K-chunk of 256).
// One-stage LDS reduction. Grid: 4 * 64 = 256 blocks.
__global__ __launch_bounds__(1024, 4) void logits_kernel(
    const __hip_bfloat16* __restrict__ act,     // [B][H] bf16
    const __hip_bfloat16* __restrict__ Wout,    // [C][H] bf16
    const float* __restrict__ bout,
    float* __restrict__ samples,                // [B][T][C] fp32 out
    __hip_bfloat16* __restrict__ codes_out,     // [B][C] bf16 out
    int t)
{
  __shared__ float red[12*64*9];   // 12 slots x 64 lanes x (8 floats + pad)

  const int tid  = threadIdx.x;
  const int lane = tid & 63;
  const int wid  = tid >> 6;
  const int ws   = wid & 3;
  const int kc   = wid >> 2;
  const int bm   = blockIdx.x & 3;
  const int bc   = blockIdx.x >> 2;
  const int m0   = bm*64 + ws*16;
  const int c0   = bc*32;
  const int rl   = lane & 15;
  const int kg   = lane >> 4;

  const __hip_bfloat16* arow = act  + (size_t)(m0+rl)*HD + kc*256 + kg*8;
  const __hip_bfloat16* w0   = Wout + (size_t)(c0+rl)*HD + kc*256 + kg*8;
  const __hip_bfloat16* w1   = w0 + (size_t)16*HD;

  f32x4 zz4 = {0.f,0.f,0.f,0.f};
  f32x4 acc0 = zz4, acc1 = zz4;

#pragma unroll 4
  for (int k = 0; k < 256; k += 32){
    bf16x8 a  = ldfrag(arow + k);
    bf16x8 f0 = ldfrag(w0 + k);
    bf16x8 f1 = ldfrag(w1 + k);
    acc0 = __builtin_amdgcn_mfma_f32_16x16x32_bf16(a, f0, acc0, 0, 0, 0);
    acc1 = __builtin_amdgcn_mfma_f32_16x16x32_bf16(a, f1, acc1, 0, 0, 0);
  }

  if (kc >= 1){
    float* p = &red[((kc-1)*4 + ws)*64*9 + lane*9];
#pragma unroll
    for (int q = 0; q < 4; q++){ p[q] = acc0[q]; p[4+q] = acc1[q]; }
  }
  __syncthreads();
  if (kc == 0){
#pragma unroll
    for (int s = 0; s < 3; s++){
      const float* p = &red[(s*4 + ws)*64*9 + lane*9];
#pragma unroll
      for (int q = 0; q < 4; q++){ acc0[q] += p[q]; acc1[q] += p[4+q]; }
    }

    const int ca = c0 + rl, cb = ca + 16;
    const float b0 = bout[ca], b1 = bout[cb];
    const int rbase = m0 + kg*4;
#pragma unroll
    for (int q = 0; q < 4; q++){
      const int brow = rbase + q;
      float s0 = sigmoidf_(acc0[q] + b0);
      float s1 = sigmoidf_(acc1[q] + b1);
      samples[(size_t)brow*TT*CC + (size_t)t*CC + ca] = s0;
      samples[(size_t)brow*TT*CC + (size_t)t*CC + cb] = s1;
      codes_out[(size_t)brow*CC + ca] = __float2bfloat16(s0);
      codes_out[(size_t)brow*CC + cb] = __float2bfloat16(s1);
    }
  }
}

extern "C" void kernel_launch(void* const* d_in, const int* in_sizes, int n_in,
                              void* d_out, int out_size, void* d_ws, size_t ws_size,
                              hipStream_t stream) {
  const float* noise = (const float*)d_in[0];
  const float* W_ih  = (const float*)d_in[1];
  const float* b_ih  = (const float*)d_in[2];
  const float* W_hh  = (const float*)d_in[3];
  const float* b_hh  = (const float*)d_in[4];
  const float* W_out = (const float*)d_in[5];
  const float* b_out = (const float*)d_in[6];

  float* samples = (float*)d_out;                       // [B][T][C]
  float* hiddens = samples + (size_t)BB*TT*CC;          // [B][T][H]

  char* w = (char*)d_ws;
  __hip_bfloat16* wih16 = (__hip_bfloat16*)w;  w += (size_t)H3*CC*2;
  __hip_bfloat16* whh16 = (__hip_bfloat16*)w;  w += (size_t)H3*HD*2;
  __hip_bfloat16* wout16= (__hip_bfloat16*)w;  w += (size_t)CC*HD*2;
  __hip_bfloat16* noise16=(__hip_bfloat16*)w;  w += (size_t)BB*HD*2;
  __hip_bfloat16* codes16=(__hip_bfloat16*)w;  w += (size_t)BB*CC*2;
  __hip_bfloat16* h16a  = (__hip_bfloat16*)w;  w += (size_t)BB*HD*2;
  __hip_bfloat16* h16b  = (__hip_bfloat16*)w;  w += (size_t)BB*HD*2;

  cvt_f32_bf16<<<2048, 256, 0, stream>>>(W_ih,  wih16,  H3*CC);
  cvt_f32_bf16<<<2048, 256, 0, stream>>>(W_hh,  whh16,  H3*HD);
  cvt_f32_bf16<<<1024, 256, 0, stream>>>(W_out, wout16, CC*HD);
  cvt_f32_bf16<<<256,  256, 0, stream>>>(noise, noise16, BB*HD);

  // samples[:,0,:] = codes0 = sigmoid(noise @ W_out^T + b_out)
  logits_kernel<<<256, 1024, 0, stream>>>(noise16, wout16, b_out, samples, codes16, 0);

  for (int t = 0; t < TT; t++){
    __hip_bfloat16* hprev = (t & 1) ? h16a : h16b;
    __hip_bfloat16* hnext = (t & 1) ? h16b : h16a;
    cell_kernel<<<256, 1024, 0, stream>>>(codes16, hprev, wih16, whh16,
                                          b_ih, b_hh, hiddens, hnext,
                                          t, (t == 0) ? 1 : 0);
    if (t < TT-1){
      logits_kernel<<<256, 1024, 0, stream>>>(hnext, wout16, b_out,
                                              samples, codes16, t+1);
    }
  }
}